// Round 5
// baseline (25.441 us; speedup 1.0000x reference)
//
#include <hip/hip_runtime.h>

// BilateralSliceApply: grid [4,12,8,16,16] f32, guide [4,1024,1024] f32,
// image [4,3,1024,1024] f32 -> out [4,3,1024,1024] f32.
//
// 2 image rows per block (even-aligned pairs always share a y-cell: band
// boundaries fall at y=64n+31.5, between odd and even rows). One raw grid
// staging load feeds two y-lerped LDS slabs; one barrier per 2 rows.
// Pixel->lane mapping p = j*256 + t keeps each wave-instr within 2 x-cells,
// so every ds_read_b128 quad-group sees <=2 distinct lines (~free).

static constexpr int C_ = 12, D_ = 8, GH_ = 16, GW_ = 16;
static constexpr int H_ = 1024, W_ = 1024;
static constexpr int HW_ = H_ * W_;
static constexpr int XS = D_ * C_ + 4;   // 100 floats; 16B-aligned x-slabs

__global__ __launch_bounds__(256) void bsa_row2_kernel(
    const float* __restrict__ grid,   // [B][C][D][GH][GW]
    const float* __restrict__ guide,  // [B][H][W]
    const float* __restrict__ image,  // [B][3][H][W]
    float* __restrict__ out)          // [B][3][H][W]
{
    __shared__ float s[2][GW_ * XS];  // 12.8 KB

    const int row0 = blockIdx.x << 1;     // global row = b*H + y, even
    const int y = row0 & (H_ - 1);        // even; y+1 in same batch & y-band
    const int b = row0 >> 10;
    const int t = threadIdx.x;

    // ---- y interpolation factors (shared raw rows; per-row ty) ----
    const float gyc0 = (y + 0.5f) * (1.0f / 64.0f) - 0.5f;
    const float fy = floorf(gyc0);        // same for y and y+1
    const float ty0 = gyc0 - fy;
    const float ty1 = ty0 + (1.0f / 64.0f);
    const int iy = (int)fy;
    const int y0 = min(max(iy, 0), GH_ - 1);
    const int y1 = min(max(iy + 1, 0), GH_ - 1);

    // ---- issue slab global loads FIRST (threads 0..191) ----
    // mapping: x = t&15, c = t>>4, z unrolled; reads 64B-coalesced per 16
    // lanes; LDS write bank = (4x + c + 12z) mod 32 -> 2-way (free).
    const int sx = t & 15, sc = t >> 4;
    float sv0[8], sv1[8];
    const float* gb = grid + b * (C_ * D_ * GH_ * GW_);
    if (t < 192) {
        const int base = sc * (D_ * GH_ * GW_) + sx;
#pragma unroll
        for (int z = 0; z < 8; ++z) {
            sv0[z] = gb[base + z * (GH_ * GW_) + y0 * GW_];
            sv1[z] = gb[base + z * (GH_ * GW_) + y1 * GW_];
        }
    }

    // ---- issue BOTH rows' pixel loads (in flight under slab write) ----
    const float* gdp = guide + (size_t)b * HW_ + (size_t)y * W_;
    const float* imp = image + (size_t)b * 3 * HW_ + (size_t)y * W_;
    float gz4[2][4], r4[2][4], g4[2][4], b4[2][4];
#pragma unroll
    for (int r = 0; r < 2; ++r) {
#pragma unroll
        for (int j = 0; j < 4; ++j) {
            const int p = r * W_ + j * 256 + t;
            gz4[r][j] = gdp[p];
            r4[r][j]  = imp[p];
            g4[r][j]  = imp[HW_ + p];
            b4[r][j]  = imp[2 * HW_ + p];
        }
    }

    // ---- y-lerp both slabs into LDS ----
    if (t < 192) {
        const int sl = sx * XS + sc;
#pragma unroll
        for (int z = 0; z < 8; ++z) {
            const float d = sv1[z] - sv0[z];
            s[0][sl + z * C_] = sv0[z] + ty0 * d;
            s[1][sl + z * C_] = sv0[z] + ty1 * d;
        }
    }
    __syncthreads();

    // ---- compute: 4 strided pixels per thread per row ----
    float* const ob = out + (size_t)b * 3 * HW_ + (size_t)y * W_;
#pragma unroll
    for (int j = 0; j < 4; ++j) {
        const int p = j * 256 + t;

        // x-cell shared by both rows
        const float gxc = (p + 0.5f) * (1.0f / 64.0f) - 0.5f;
        const float fx = floorf(gxc);
        const float tx = gxc - fx;
        const int ix = (int)fx;
        const int x0 = min(max(ix, 0), GW_ - 1);
        const int x1 = min(max(ix + 1, 0), GW_ - 1);

#pragma unroll
        for (int r = 0; r < 2; ++r) {
            const float gz = gz4[r][j] * (float)D_ - 0.5f;
            const float fz = floorf(gz);
            const float tz = gz - fz;
            const int iz = (int)fz;
            const int z0 = min(max(iz, 0), D_ - 1);
            const int z1 = min(max(iz + 1, 0), D_ - 1);

            const float w00 = (1.f - tx) * (1.f - tz);
            const float w01 = (1.f - tx) * tz;
            const float w10 = tx * (1.f - tz);
            const float w11 = tx * tz;

            const float* sb = s[r];
            const float* p00 = sb + x0 * XS + z0 * C_;
            const float* p01 = sb + x0 * XS + z1 * C_;
            const float* p10 = sb + x1 * XS + z0 * C_;
            const float* p11 = sb + x1 * XS + z1 * C_;

            const float rv = r4[r][j], gv = g4[r][j], bv = b4[r][j];

#pragma unroll
            for (int k = 0; k < 3; ++k) {
                float4 a0 = *(const float4*)(p00 + 4 * k);
                float4 a1 = *(const float4*)(p01 + 4 * k);
                float4 a2 = *(const float4*)(p10 + 4 * k);
                float4 a3 = *(const float4*)(p11 + 4 * k);
                float cx = w00 * a0.x + w01 * a1.x + w10 * a2.x + w11 * a3.x;
                float cy = w00 * a0.y + w01 * a1.y + w10 * a2.y + w11 * a3.y;
                float cz = w00 * a0.z + w01 * a1.z + w10 * a2.z + w11 * a3.z;
                float cw = w00 * a0.w + w01 * a1.w + w10 * a2.w + w11 * a3.w;
                ob[(size_t)k * HW_ + r * W_ + p] = cx * rv + cy * gv + cz * bv + cw;
            }
        }
    }
}

extern "C" void kernel_launch(void* const* d_in, const int* in_sizes, int n_in,
                              void* d_out, int out_size, void* d_ws, size_t ws_size,
                              hipStream_t stream) {
    const float* grid  = (const float*)d_in[0];
    const float* guide = (const float*)d_in[1];
    const float* image = (const float*)d_in[2];
    float* out = (float*)d_out;

    bsa_row2_kernel<<<(4 * H_) / 2, 256, 0, stream>>>(grid, guide, image, out);
}